// Round 2
// baseline (472.592 us; speedup 1.0000x reference)
//
#include <hip/hip_runtime.h>

// nnmodel_35708358099045 R2: LDS-staged coalesced version.
// One wave (64 threads) per block, one batch element per thread, tile = 64
// elements. All global traffic is lane-contiguous float4 (1 KiB/inst).
// LDS buffer (64 x 44 floats = 11264 B) is reused across phases:
//   phase X : stage x tile  -> compute agg[10]/thread
//   phase ZA: stage z nodes 0..4 -> encoder rows 0..4, emit s2[1..3]
//   phase ZB: stage z nodes 5..9 -> rows 5..9, emit s2[4..9], s2[0]
//   phase O : write out-partials to LDS, final coalesced pass
//             out = partial + y*droot  (y read coalesced, never staged)
// Streaming predictor keeps a rolling window of z1 rows (never all 10)
// to hold VGPRs ~<=128 (launch_bounds caps at 4 waves/SIMD).

#define HN 10
#define ND 40
#define HF 8
#define TPB 64
#define ROWF 44   // padded LDS row stride in floats (16B-aligned, breaks pow2 banks)
#define ROW4 11   // same in float4

__global__ __launch_bounds__(TPB, 4) void gnn_kernel(
    const float* __restrict__ x,          // [B, 40]
    const float* __restrict__ z,          // [B, 10, 8]
    const float* __restrict__ y,          // [B, 40]
    const float* __restrict__ enc_rel_w,  // [8, 1]
    const float* __restrict__ enc_rel_b,  // [8]
    const float* __restrict__ enc_root_w, // [8, 8]
    const float* __restrict__ pred_rel_w, // [8, 8]
    const float* __restrict__ pred_rel_b, // [8]
    const float* __restrict__ pred_root_w,// [8, 8]
    const float* __restrict__ dec_rel_w,  // [1, 8]
    const float* __restrict__ dec_rel_b,  // [1]
    const float* __restrict__ dec_root_w, // [1, 1]
    float* __restrict__ out,              // [B, 40]
    int B)
{
    __shared__ float lds[TPB * ROWF];
    float4* lds4 = (float4*)lds;
    const int t = threadIdx.x;
    const long long tile = (long long)blockIdx.x * TPB;   // B % 64 == 0

    const float w = 0.8948393168143698f;  // exp(-(1/3)^2) as fp32

    // ---------- phase X: stage x tile (coalesced) ----------
    const float4* xg = (const float4*)(x + tile * ND);
    #pragma unroll
    for (int k = 0; k < 10; ++k) {
        int i = t + TPB * k;              // 0..639
        int e = i / 10, q = i - e * 10;   // elem-in-tile, float4-in-row
        lds4[e * ROW4 + q] = xg[i];
    }
    __syncthreads();

    // encoder aggregation from LDS row
    float agg[HN];
    {
        float xv[ND];
        #pragma unroll
        for (int k = 0; k < ND; ++k) xv[k] = lds[t * ROWF + k];
        agg[0] = xv[37] + xv[38] + xv[39] + xv[0] + xv[1] + xv[2];
        #pragma unroll
        for (int j = 1; j < HN; ++j)
            agg[j] = xv[4*j-3] + xv[4*j-2] + xv[4*j-1] + xv[4*j] + xv[4*j+1] + xv[4*j+2];
    }
    __syncthreads();

    // z1 row computation from LDS z-row at node-slot jj (0..4 within phase)
    auto enc_row = [&](int jj, int j, float (&r)[HF]) {
        float4 v0 = lds4[t * ROW4 + jj * 2];
        float4 v1 = lds4[t * ROW4 + jj * 2 + 1];
        float zr[HF] = {v0.x, v0.y, v0.z, v0.w, v1.x, v1.y, v1.z, v1.w};
        #pragma unroll
        for (int f = 0; f < HF; ++f) {
            float acc = agg[j] * enc_rel_w[f] + enc_rel_b[f];
            #pragma unroll
            for (int g = 0; g < HF; ++g)
                acc += zr[g] * enc_root_w[f * HF + g];
            r[f] = fmaxf(acc, 0.0f);
        }
    };

    // predictor + decoder-dot: s2[j] from z1 rows (jm, j, jp)
    auto emit = [&](const float (&rm)[HF], const float (&rc)[HF],
                    const float (&rp)[HF]) -> float {
        float a2[HF];
        #pragma unroll
        for (int f = 0; f < HF; ++f)
            a2[f] = rc[f] + w * (rm[f] + rp[f]);
        float s = 0.0f;
        #pragma unroll
        for (int f = 0; f < HF; ++f) {
            float acc = pred_rel_b[f];
            #pragma unroll
            for (int g = 0; g < HF; ++g)
                acc += a2[g] * pred_rel_w[f * HF + g];
            #pragma unroll
            for (int g = 0; g < HF; ++g)
                acc += rc[g] * pred_root_w[f * HF + g];
            s += fmaxf(acc, 0.0f) * dec_rel_w[f];
        }
        return s;
    };

    const float4* zg = (const float4*)(z + tile * (HN * HF));
    float s2[HN];

    // ---------- phase ZA: stage z nodes 0..4, rows 0..4 ----------
    #pragma unroll
    for (int k = 0; k < 10; ++k) {
        int i = t + TPB * k;
        int e = i / 10, q = i - e * 10;
        lds4[e * ROW4 + q] = zg[e * 20 + q];          // first half of row
    }
    __syncthreads();

    float rA[5][HF];
    #pragma unroll
    for (int jj = 0; jj < 5; ++jj) enc_row(jj, jj, rA[jj]);
    s2[1] = emit(rA[0], rA[1], rA[2]);
    s2[2] = emit(rA[1], rA[2], rA[3]);
    s2[3] = emit(rA[2], rA[3], rA[4]);
    __syncthreads();   // all z reads done before overwrite

    // ---------- phase ZB: stage z nodes 5..9, rows 5..9 ----------
    #pragma unroll
    for (int k = 0; k < 10; ++k) {
        int i = t + TPB * k;
        int e = i / 10, q = i - e * 10;
        lds4[e * ROW4 + q] = zg[e * 20 + 10 + q];     // second half of row
    }
    __syncthreads();

    float rB[5][HF];
    #pragma unroll
    for (int jj = 0; jj < 5; ++jj) enc_row(jj, 5 + jj, rB[jj]);
    s2[4] = emit(rA[3], rA[4], rB[0]);
    s2[5] = emit(rA[4], rB[0], rB[1]);
    s2[6] = emit(rB[0], rB[1], rB[2]);
    s2[7] = emit(rB[1], rB[2], rB[3]);
    s2[8] = emit(rB[2], rB[3], rB[4]);
    s2[9] = emit(rB[3], rB[4], rA[0]);
    s2[0] = emit(rB[4], rA[0], rA[1]);
    __syncthreads();   // all z reads done before overwrite

    // ---------- phase O: partials to LDS (linear stride-40 layout) ----------
    const float drb = dec_rel_b[0];
    const float droot = dec_root_w[0];
    #pragma unroll
    for (int k = 0; k < 10; ++k) {
        const int k1 = (k + 1) % HN;
        const float pair = s2[k] + s2[k1] + drb;
        lds[t * ND + 4*k + 0] = s2[k] + drb;
        lds[t * ND + 4*k + 1] = pair;
        lds[t * ND + 4*k + 2] = pair;
        lds[t * ND + 4*k + 3] = s2[k1] + drb;
    }
    __syncthreads();

    // final coalesced pass: out = partial + y * droot
    const float4* yg = (const float4*)(y + tile * ND);
    float4* og = (float4*)(out + tile * ND);
    #pragma unroll
    for (int k = 0; k < 10; ++k) {
        int i = t + TPB * k;
        float4 p = lds4[i];
        float4 vy = yg[i];
        p.x += vy.x * droot;
        p.y += vy.y * droot;
        p.z += vy.z * droot;
        p.w += vy.w * droot;
        og[i] = p;
    }
}

extern "C" void kernel_launch(void* const* d_in, const int* in_sizes, int n_in,
                              void* d_out, int out_size, void* d_ws, size_t ws_size,
                              hipStream_t stream) {
    const float* x          = (const float*)d_in[0];
    const float* z          = (const float*)d_in[1];
    const float* y          = (const float*)d_in[2];
    const float* enc_rel_w  = (const float*)d_in[3];
    const float* enc_rel_b  = (const float*)d_in[4];
    const float* enc_root_w = (const float*)d_in[5];
    const float* pred_rel_w = (const float*)d_in[6];
    const float* pred_rel_b = (const float*)d_in[7];
    const float* pred_root_w= (const float*)d_in[8];
    const float* dec_rel_w  = (const float*)d_in[9];
    const float* dec_rel_b  = (const float*)d_in[10];
    const float* dec_root_w = (const float*)d_in[11];
    float* out = (float*)d_out;

    const int B = in_sizes[0] / ND;       // 524288, divisible by TPB
    const int blocks = B / TPB;
    gnn_kernel<<<blocks, TPB, 0, stream>>>(
        x, z, y, enc_rel_w, enc_rel_b, enc_root_w,
        pred_rel_w, pred_rel_b, pred_root_w,
        dec_rel_w, dec_rel_b, dec_root_w, out, B);
}

// Round 3
// 421.727 us; speedup vs baseline: 1.1206x; 1.1206x over previous
//
#include <hip/hip_runtime.h>

// nnmodel_35708358099045 R3: R2 structure, spills + bank conflicts fixed.
// - NO VGPR cap (R2's __launch_bounds__(64,4) forced 64 VGPRs -> ~176 MB of
//   scratch spill writes; WRITE_SIZE 260 MB vs ideal 84 MB).
// - All LDS traffic is ds_read_b128/ds_write_b128 on a padded layout of
//   11 float4 per row: float4-group = 3t mod 8 is a permutation of 0..7
//   across 8 consecutive lanes -> conflict-free b128.
// - Out partials staged as float4 in the same padded layout, drained with
//   computed (e*11+q) addressing (near-sequential -> conflict-free).

#define HN 10
#define ND 40
#define HF 8
#define TPB 64
#define ROW4 11   // padded LDS row stride in float4 (odd -> no b128 conflicts)

__global__ __launch_bounds__(TPB) void gnn_kernel(
    const float* __restrict__ x,          // [B, 40]
    const float* __restrict__ z,          // [B, 10, 8]
    const float* __restrict__ y,          // [B, 40]
    const float* __restrict__ enc_rel_w,  // [8, 1]
    const float* __restrict__ enc_rel_b,  // [8]
    const float* __restrict__ enc_root_w, // [8, 8]
    const float* __restrict__ pred_rel_w, // [8, 8]
    const float* __restrict__ pred_rel_b, // [8]
    const float* __restrict__ pred_root_w,// [8, 8]
    const float* __restrict__ dec_rel_w,  // [1, 8]
    const float* __restrict__ dec_rel_b,  // [1]
    const float* __restrict__ dec_root_w, // [1, 1]
    float* __restrict__ out,              // [B, 40]
    int B)
{
    __shared__ float4 lds4[TPB * ROW4];   // 11264 B
    const int t = threadIdx.x;
    const long long tile = (long long)blockIdx.x * TPB;   // B % 64 == 0

    const float w = 0.8948393168143698f;  // exp(-(1/3)^2) as fp32

    // ---------- phase X: stage x tile (coalesced global, padded LDS) ----------
    const float4* xg = (const float4*)(x + tile * ND);
    #pragma unroll
    for (int k = 0; k < 10; ++k) {
        int i = t + TPB * k;              // 0..639
        int e = i / 10, q = i - e * 10;   // elem-in-tile, float4-in-row
        lds4[e * ROW4 + q] = xg[i];
    }
    __syncthreads();

    // encoder aggregation: read own row as 10 x b128 (conflict-free), unpack
    float agg[HN];
    {
        float xv[ND];
        #pragma unroll
        for (int k = 0; k < 10; ++k) {
            float4 v = lds4[t * ROW4 + k];
            xv[4*k+0] = v.x; xv[4*k+1] = v.y; xv[4*k+2] = v.z; xv[4*k+3] = v.w;
        }
        agg[0] = xv[37] + xv[38] + xv[39] + xv[0] + xv[1] + xv[2];
        #pragma unroll
        for (int j = 1; j < HN; ++j)
            agg[j] = xv[4*j-3] + xv[4*j-2] + xv[4*j-1] + xv[4*j] + xv[4*j+1] + xv[4*j+2];
    }
    __syncthreads();

    // z1 row: encoder GraphConv from LDS z-row at slot jj (node j)
    auto enc_row = [&](int jj, int j, float (&r)[HF]) {
        float4 v0 = lds4[t * ROW4 + jj * 2];
        float4 v1 = lds4[t * ROW4 + jj * 2 + 1];
        float zr[HF] = {v0.x, v0.y, v0.z, v0.w, v1.x, v1.y, v1.z, v1.w};
        #pragma unroll
        for (int f = 0; f < HF; ++f) {
            float acc = agg[j] * enc_rel_w[f] + enc_rel_b[f];
            #pragma unroll
            for (int g = 0; g < HF; ++g)
                acc += zr[g] * enc_root_w[f * HF + g];
            r[f] = fmaxf(acc, 0.0f);
        }
    };

    // predictor + decoder row-dot: s2 for center row rc with neighbors rm, rp
    auto emit = [&](const float (&rm)[HF], const float (&rc)[HF],
                    const float (&rp)[HF]) -> float {
        float a2[HF];
        #pragma unroll
        for (int f = 0; f < HF; ++f)
            a2[f] = rc[f] + w * (rm[f] + rp[f]);
        float s = 0.0f;
        #pragma unroll
        for (int f = 0; f < HF; ++f) {
            float acc = pred_rel_b[f];
            #pragma unroll
            for (int g = 0; g < HF; ++g)
                acc += a2[g] * pred_rel_w[f * HF + g];
            #pragma unroll
            for (int g = 0; g < HF; ++g)
                acc += rc[g] * pred_root_w[f * HF + g];
            s += fmaxf(acc, 0.0f) * dec_rel_w[f];
        }
        return s;
    };

    const float4* zg = (const float4*)(z + tile * (HN * HF));
    float s2[HN];

    // ---------- phase ZA: stage z nodes 0..4 (rows' first 160 B) ----------
    #pragma unroll
    for (int k = 0; k < 10; ++k) {
        int i = t + TPB * k;
        int e = i / 10, q = i - e * 10;
        lds4[e * ROW4 + q] = zg[e * 20 + q];
    }
    __syncthreads();

    float rA[5][HF];
    #pragma unroll
    for (int jj = 0; jj < 5; ++jj) enc_row(jj, jj, rA[jj]);
    s2[1] = emit(rA[0], rA[1], rA[2]);
    s2[2] = emit(rA[1], rA[2], rA[3]);
    s2[3] = emit(rA[2], rA[3], rA[4]);
    __syncthreads();

    // ---------- phase ZB: stage z nodes 5..9 ----------
    #pragma unroll
    for (int k = 0; k < 10; ++k) {
        int i = t + TPB * k;
        int e = i / 10, q = i - e * 10;
        lds4[e * ROW4 + q] = zg[e * 20 + 10 + q];
    }
    __syncthreads();

    float rB[5][HF];
    #pragma unroll
    for (int jj = 0; jj < 5; ++jj) enc_row(jj, 5 + jj, rB[jj]);
    s2[4] = emit(rA[3], rA[4], rB[0]);
    s2[5] = emit(rA[4], rB[0], rB[1]);
    s2[6] = emit(rB[0], rB[1], rB[2]);
    s2[7] = emit(rB[1], rB[2], rB[3]);
    s2[8] = emit(rB[2], rB[3], rB[4]);
    s2[9] = emit(rB[3], rB[4], rA[0]);
    s2[0] = emit(rB[4], rA[0], rA[1]);
    __syncthreads();

    // ---------- phase O: stage out partials as float4 (padded layout) ----------
    const float drb = dec_rel_b[0];
    const float droot = dec_root_w[0];
    #pragma unroll
    for (int k = 0; k < 10; ++k) {
        const int k1 = (k + 1) % HN;
        const float pair = s2[k] + s2[k1] + drb;
        float4 vo;
        vo.x = s2[k] + drb;
        vo.y = pair;
        vo.z = pair;
        vo.w = s2[k1] + drb;
        lds4[t * ROW4 + k] = vo;        // b128, stride 11 -> conflict-free
    }
    __syncthreads();

    // drain: out = partial + y * droot, fully coalesced global float4
    const float4* yg = (const float4*)(y + tile * ND);
    float4* og = (float4*)(out + tile * ND);
    #pragma unroll
    for (int k = 0; k < 10; ++k) {
        int i = t + TPB * k;
        int e = i / 10, q = i - e * 10;
        float4 p = lds4[e * ROW4 + q];  // near-sequential addrs -> conflict-free
        float4 vy = yg[i];
        p.x += vy.x * droot;
        p.y += vy.y * droot;
        p.z += vy.z * droot;
        p.w += vy.w * droot;
        og[i] = p;
    }
}

extern "C" void kernel_launch(void* const* d_in, const int* in_sizes, int n_in,
                              void* d_out, int out_size, void* d_ws, size_t ws_size,
                              hipStream_t stream) {
    const float* x          = (const float*)d_in[0];
    const float* z          = (const float*)d_in[1];
    const float* y          = (const float*)d_in[2];
    const float* enc_rel_w  = (const float*)d_in[3];
    const float* enc_rel_b  = (const float*)d_in[4];
    const float* enc_root_w = (const float*)d_in[5];
    const float* pred_rel_w = (const float*)d_in[6];
    const float* pred_rel_b = (const float*)d_in[7];
    const float* pred_root_w= (const float*)d_in[8];
    const float* dec_rel_w  = (const float*)d_in[9];
    const float* dec_rel_b  = (const float*)d_in[10];
    const float* dec_root_w = (const float*)d_in[11];
    float* out = (float*)d_out;

    const int B = in_sizes[0] / ND;       // 524288, divisible by TPB
    const int blocks = B / TPB;
    gnn_kernel<<<blocks, TPB, 0, stream>>>(
        x, z, y, enc_rel_w, enc_rel_b, enc_root_w,
        pred_rel_w, pred_rel_b, pred_root_w,
        dec_rel_w, dec_rel_b, dec_root_w, out, B);
}